// Round 13
// baseline (277.653 us; speedup 1.0000x reference)
//
#include <hip/hip_runtime.h>
#include <hip/hip_bf16.h>
#include <math.h>

#define AS1 __attribute__((address_space(1)))
#define AS3 __attribute__((address_space(3)))

typedef __bf16  bf16x8 __attribute__((ext_vector_type(8)));
typedef float   f32x4  __attribute__((ext_vector_type(4)));
typedef __hip_bfloat16 bf16;

__device__ __forceinline__ void gload_lds16(const void* g, void* l) {
  __builtin_amdgcn_global_load_lds((const AS1 void*)g, (AS3 void*)l, 16, 0, 0);
}

// ---------------- weight conversion f32 -> bf16 ----------------
__global__ __launch_bounds__(256) void k_conv_weights(
    const float* __restrict__ qkvw, const float* __restrict__ projw,
    const float* __restrict__ w1, const float* __restrict__ w2,
    bf16* __restrict__ dst)
{
  int i = blockIdx.x * 256 + threadIdx.x;   // grid covers exactly 786432
  float v;
  if (i < 196608)       v = qkvw[i];
  else if (i < 262144)  v = projw[i - 196608];
  else if (i < 524288)  v = w1[i - 262144];
  else                  v = w2[i - 524288];
  dst[i] = __float2bfloat16(v);
}

// ---------------- rel-pos bias table: btab[h][n][m] ----------------
__global__ __launch_bounds__(256) void k_build_btab(
    const float* __restrict__ rel_bias, float* __restrict__ btab)
{
  int i = blockIdx.x * 256 + threadIdx.x;   // 32768
  int h = i >> 12, r = i & 4095, n = r >> 6, m = r & 63;
  int idx = ((n >> 3) - (m >> 3) + 7) * 15 + ((n & 7) - (m & 7) + 7);
  btab[i] = rel_bias[idx * 8 + h];
}

// ---- LN1 + roll(-4,-4) + window partition, f32 -> bf16 (PRE-SWIZZLED rows) ----
// row t stored at bytes t*512 + ((col*2) ^ ((t&7)<<4)) so linear DMA->LDS keeps
// the XOR swizzle needed for conflict-free MFMA fragment reads.
__global__ __launch_bounds__(256) void k_ln1_window(
    const float* __restrict__ x, const float* __restrict__ sc,
    const float* __restrict__ bi, bf16* __restrict__ hout)
{
  int t = blockIdx.x * 4 + (threadIdx.x >> 6);
  int lane = threadIdx.x & 63;
  int win = t >> 6, nn = t & 63;
  int b = win >> 6, ww = win & 63;
  int ry = ((ww >> 3) << 3) + (nn >> 3);
  int rx = ((ww & 7) << 3) + (nn & 7);
  int sy = (ry + 4) & 63, sx = (rx + 4) & 63;
  const float* src = x + ((size_t)(((b << 6) + sy) << 6) + sx) * 256;
  f32x4 v = *(const f32x4*)(src + lane * 4);
  float s = v[0] + v[1] + v[2] + v[3];
  #pragma unroll
  for (int o = 1; o < 64; o <<= 1) s += __shfl_xor(s, o);
  float mu = s * (1.0f / 256.0f);
  float d0 = v[0]-mu, d1 = v[1]-mu, d2 = v[2]-mu, d3 = v[3]-mu;
  float q = d0*d0 + d1*d1 + d2*d2 + d3*d3;
  #pragma unroll
  for (int o = 1; o < 64; o <<= 1) q += __shfl_xor(q, o);
  float rstd = rsqrtf(q * (1.0f / 256.0f) + 1e-5f);
  int c = lane * 4;
  union { bf16 h[4]; uint2 u; } pk;
  pk.h[0] = __float2bfloat16(d0 * rstd * sc[c+0] + bi[c+0]);
  pk.h[1] = __float2bfloat16(d1 * rstd * sc[c+1] + bi[c+1]);
  pk.h[2] = __float2bfloat16(d2 * rstd * sc[c+2] + bi[c+2]);
  pk.h[3] = __float2bfloat16(d3 * rstd * sc[c+3] + bi[c+3]);
  *(uint2*)((char*)hout + (size_t)t * 512 + ((lane * 8) ^ ((t & 7) << 4))) = pk.u;
}

// ================= FUSED window kernel: QKV + attention + proj + LN2 =================
// One block per window (64 tokens). 4 waves. 40 phases, each consuming one staged
// 16KB group (W-chunk or bias table slice), staged 2 phases ahead into a 3-slot ring
// (sb has its own buffer). All prefetchable globals are software-pipelined into
// registers so no mid-phase vmcnt drains; conservative vmcnt(4)+lgkmcnt(0) per phase.
__global__ __launch_bounds__(256, 1) void k_win(
    const bf16* __restrict__ hbuf, const bf16* __restrict__ wqkv,
    const float* __restrict__ qkv_b, const float* __restrict__ btab,
    const bf16* __restrict__ wproj, const float* __restrict__ proj_b,
    const float* __restrict__ xres, const float* __restrict__ ln2s,
    const float* __restrict__ ln2b, float* __restrict__ X1,
    bf16* __restrict__ ln2out)
{
  __shared__ __align__(16) char lds[156160];
  char* ring = lds;                        // 3 x 16384
  char* ldsH = lds + 49152;                // 32768: h tile, later x1 bf16 copy
  char* obuf = lds + 81920;                // 32768: attn out [64][512B] swizzled
  char* sbuf = lds + 114688;               // 16384: btab head slice (f32 [64][64])
  char* qb   = lds + 131072;               // 5120: Q bounce [64][80B]
  char* kb   = lds + 136192;               // 5120: K bounce
  char* vt   = lds + 141312;               // 4608: V^T [32][144B]
  char* plwA = lds + 145920;               // 4 x 2304: per-wave P [16][144B]
  float* sums = (float*)(lds + 155136);    // [64 rows][2 halves] float2

  const int tid = threadIdx.x;
  const int wid = tid >> 6;
  const int lane = tid & 63;
  const int l15 = lane & 15, lh = lane >> 4;
  const int wr = (wid >> 1) * 32;          // row half (gemm phases)
  const int wn = (wid & 1) * 16;           // col half within 32-col chunk
  const int win = blockIdx.x;
  const int tb = win << 6;
  char* plw = plwA + wid * 2304;
  const int xr = (l15 & 7) << 4;

  auto stageAt = [&](int i) {   // data consumed at phase i; 4 ops/thread, uniform
    if (i < 32 && (i & 3) == 3) {
      const char* src = (const char*)btab + (size_t)(i >> 2) * 16384;
      #pragma unroll
      for (int q = 0; q < 4; ++q) {
        int off = (q * 256 + tid) * 16;
        gload_lds16(src + off, sbuf + off);
      }
    } else {
      char* dst = ring + (i % 3) * 16384;
      const char* wsrc;
      if (i < 32) { int hh = i >> 2, rr = i & 3;
                    wsrc = (const char*)(wqkv + (size_t)(rr * 256 + hh * 32) * 256); }
      else        { wsrc = (const char*)(wproj + (size_t)(i - 32) * 32 * 256); }
      #pragma unroll
      for (int q = 0; q < 4; ++q) {
        int off = (q * 256 + tid) * 16;
        int rr2 = off >> 9, cb = off & 511;
        int csw = cb ^ ((rr2 & 7) << 4);
        gload_lds16(wsrc + (size_t)rr2 * 512 + csw, dst + off);
      }
    }
  };

  auto remap = [&](int row) -> size_t {    // window token -> pixel-major elem offset
    int w2 = row >> 6, nn2 = row & 63;
    int b2 = w2 >> 6, ww3 = w2 & 63;
    int ry = ((ww3 >> 3) << 3) + (nn2 >> 3);
    int rx = ((ww3 & 7) << 3) + (nn2 & 7);
    int fy = (ry + 4) & 63, fx = (rx + 4) & 63;
    return ((size_t)(((b2 << 6) + fy) << 6) + fx) * 256;
  };

  // ---- prologue ----
  f32x4 bcur = *(const f32x4*)(qkv_b + wn + lh * 4);     // chunk (h=0, r=0)
  {
    const char* src = (const char*)hbuf + (size_t)win * 32768;
    #pragma unroll
    for (int q = 0; q < 8; ++q) {
      int off = (q * 256 + tid) * 16;
      gload_lds16(src + off, ldsH + off);
    }
  }
  stageAt(0);
  stageAt(1);
  asm volatile("s_waitcnt vmcnt(4)" ::: "memory");       // bcur, h, s(0) done
  __builtin_amdgcn_sched_barrier(0);

  // attention mask labels (keys)
  const int ww2 = win & 63, wi2 = ww2 >> 3, wj2 = ww2 & 7;
  int labm[4];
  #pragma unroll
  for (int jf = 0; jf < 4; ++jf) {
    int m = jf * 16 + l15;
    int yy = wi2 * 8 + (m >> 3), xx = wj2 * 8 + (m & 7);
    labm[jf] = (yy < 56 ? 0 : (yy < 60 ? 1 : 2)) * 3 + (xx < 56 ? 0 : (xx < 60 ? 1 : 2));
  }

  bf16x8 afQ[2][8];
  f32x4 pbR, rR0, rR1;                     // proj operand pipeline
  const size_t pixA0 = remap(tb + wr + l15);
  const size_t pixA1 = remap(tb + wr + 16 + l15);

  // ======== 8 head groups: [C,C,C,A] ========
  for (int h = 0; h < 8; ++h) {
    for (int r = 0; r < 3; ++r) {
      const int p = h * 4 + r;
      __builtin_amdgcn_s_barrier();
      __builtin_amdgcn_sched_barrier(0);
      f32x4 bnext;
      if (r < 2) bnext = *(const f32x4*)(qkv_b + (r + 1) * 256 + h * 32 + wn + lh * 4);
      stageAt(p + 2);
      if (p == 0) {                        // one-time A fragments from h tile
        #pragma unroll
        for (int kk = 0; kk < 8; ++kk) {
          int rA0 = wr + l15, rA1 = wr + 16 + l15;
          afQ[0][kk] = *(const bf16x8*)(ldsH + rA0 * 512 + ((lh*16 + kk*64) ^ ((rA0 & 7) << 4)));
          afQ[1][kk] = *(const bf16x8*)(ldsH + rA1 * 512 + ((lh*16 + kk*64) ^ ((rA1 & 7) << 4)));
        }
      }
      const char* buf = ring + (p % 3) * 16384;
      f32x4 a0 = (f32x4){0.f,0.f,0.f,0.f};
      f32x4 a1 = (f32x4){0.f,0.f,0.f,0.f};
      #pragma unroll
      for (int kk = 0; kk < 8; ++kk) {
        bf16x8 wf = *(const bf16x8*)(buf + (wn + l15) * 512 + ((kk*64 + lh*16) ^ xr));
        a0 = __builtin_amdgcn_mfma_f32_16x16x32_bf16(wf, afQ[0][kk], a0, 0, 0, 0);
        a1 = __builtin_amdgcn_mfma_f32_16x16x32_bf16(wf, afQ[1][kk], a1, 0, 0, 0);
      }
      if (r < 2) {                         // Q/K -> bounce tiles
        char* dstb = (r == 0) ? qb : kb;
        union { bf16 hh[4]; uint2 u; } p0, p1;
        #pragma unroll
        for (int j = 0; j < 4; ++j) {
          p0.hh[j] = __float2bfloat16(a0[j] + bcur[j]);
          p1.hh[j] = __float2bfloat16(a1[j] + bcur[j]);
        }
        *(uint2*)(dstb + (wr + l15) * 80 + (wn + lh*4) * 2)      = p0.u;
        *(uint2*)(dstb + (wr + 16 + l15) * 80 + (wn + lh*4) * 2) = p1.u;
        bcur = bnext;
      } else {                             // V -> transposed tile
        #pragma unroll
        for (int j = 0; j < 4; ++j) {
          *(bf16*)(vt + (wn + lh*4 + j) * 144 + (wr + l15) * 2)      = __float2bfloat16(a0[j] + bcur[j]);
          *(bf16*)(vt + (wn + lh*4 + j) * 144 + (wr + 16 + l15) * 2) = __float2bfloat16(a1[j] + bcur[j]);
        }
      }
      asm volatile("s_waitcnt vmcnt(4) lgkmcnt(0)" ::: "memory");
      __builtin_amdgcn_sched_barrier(0);
    }
    {   // ---- attention phase for head h ----
      const int p = h * 4 + 3;
      __builtin_amdgcn_s_barrier();
      __builtin_amdgcn_sched_barrier(0);
      f32x4 bnext;
      if (h < 7) bnext = *(const f32x4*)(qkv_b + (h + 1) * 32 + wn + lh * 4);
      else {                               // prefetch proj chunk-0 operands
        pbR = *(const f32x4*)(proj_b + wn + lh * 4);
        rR0 = *(const f32x4*)(xres + pixA0 + wn + lh * 4);
        rR1 = *(const f32x4*)(xres + pixA1 + wn + lh * 4);
      }
      stageAt(p + 2);

      bf16x8 qf = *(const bf16x8*)(qb + (wid*16 + l15) * 80 + lh * 16);
      bf16x8 kf[4];
      f32x4 sj[4];
      #pragma unroll
      for (int jf = 0; jf < 4; ++jf) {
        kf[jf] = *(const bf16x8*)(kb + (jf*16 + l15) * 80 + lh * 16);
        f32x4 z = (f32x4){0.f,0.f,0.f,0.f};
        sj[jf] = __builtin_amdgcn_mfma_f32_16x16x32_bf16(qf, kf[jf], z, 0, 0, 0);
      }
      const float scale = 0.17677669529663687f;   // 1/sqrt(32)
      float rsum[4];
      #pragma unroll
      for (int j = 0; j < 4; ++j) {
        int n = wid*16 + lh*4 + j;
        int yy = wi2*8 + (n >> 3), xx = wj2*8 + (n & 7);
        int labn = (yy < 56 ? 0 : (yy < 60 ? 1 : 2)) * 3 + (xx < 56 ? 0 : (xx < 60 ? 1 : 2));
        float vals[4]; float mx = -1e30f;
        #pragma unroll
        for (int jf = 0; jf < 4; ++jf) {
          float v = sj[jf][j] * scale + ((const float*)sbuf)[(n << 6) + jf*16 + l15];
          if (labn != labm[jf]) v -= 100.0f;
          vals[jf] = v; mx = fmaxf(mx, v);
        }
        #pragma unroll
        for (int o = 1; o < 16; o <<= 1) mx = fmaxf(mx, __shfl_xor(mx, o));
        float sum = 0.0f;
        #pragma unroll
        for (int jf = 0; jf < 4; ++jf) {
          float e = __expf(vals[jf] - mx);
          sum += e;
          *(bf16*)(plw + (lh*4 + j) * 144 + (jf*16 + l15) * 2) = __float2bfloat16(e);
        }
        #pragma unroll
        for (int o = 1; o < 16; o <<= 1) sum += __shfl_xor(sum, o);
        rsum[j] = sum;
      }
      f32x4 o0 = (f32x4){0.f,0.f,0.f,0.f};
      f32x4 o1 = (f32x4){0.f,0.f,0.f,0.f};
      #pragma unroll
      for (int kk = 0; kk < 2; ++kk) {
        bf16x8 pf  = *(const bf16x8*)(plw + l15 * 144 + kk*64 + lh*16);
        bf16x8 vf0 = *(const bf16x8*)(vt + l15 * 144 + kk*64 + lh*16);
        bf16x8 vf1 = *(const bf16x8*)(vt + (16 + l15) * 144 + kk*64 + lh*16);
        o0 = __builtin_amdgcn_mfma_f32_16x16x32_bf16(pf, vf0, o0, 0, 0, 0);
        o1 = __builtin_amdgcn_mfma_f32_16x16x32_bf16(pf, vf1, o1, 0, 0, 0);
      }
      #pragma unroll
      for (int j = 0; j < 4; ++j) {
        int grow = wid*16 + lh*4 + j;
        int xg = (grow & 7) << 4;
        *(bf16*)(obuf + grow*512 + (((h*32 + l15) * 2) ^ xg))      = __float2bfloat16(o0[j] / rsum[j]);
        *(bf16*)(obuf + grow*512 + (((h*32 + 16 + l15) * 2) ^ xg)) = __float2bfloat16(o1[j] / rsum[j]);
      }
      if (h < 7) bcur = bnext;
      asm volatile("s_waitcnt vmcnt(4) lgkmcnt(0)" ::: "memory");
      __builtin_amdgcn_sched_barrier(0);
    }
  }

  // ======== proj phases (8 chunks of 32 cols) + LN2 ========
  bf16x8 paf[2][8];
  float ls0 = 0.f, lq0 = 0.f, ls1 = 0.f, lq1 = 0.f;
  for (int j = 0; j < 8; ++j) {
    const int p = 32 + j;
    __builtin_amdgcn_s_barrier();
    __builtin_amdgcn_sched_barrier(0);
    f32x4 pbN, rN0, rN1;
    if (j < 7) {
      int ncol = (j + 1) * 32 + wn + lh * 4;
      pbN = *(const f32x4*)(proj_b + ncol);
      rN0 = *(const f32x4*)(xres + pixA0 + ncol);
      rN1 = *(const f32x4*)(xres + pixA1 + ncol);
    }
    if (p + 2 < 40) stageAt(p + 2);
    if (j == 0) {
      #pragma unroll
      for (int kk = 0; kk < 8; ++kk) {
        int rA0 = wr + l15, rA1 = wr + 16 + l15;
        paf[0][kk] = *(const bf16x8*)(obuf + rA0 * 512 + ((lh*16 + kk*64) ^ ((rA0 & 7) << 4)));
        paf[1][kk] = *(const bf16x8*)(obuf + rA1 * 512 + ((lh*16 + kk*64) ^ ((rA1 & 7) << 4)));
      }
    }
    const char* buf = ring + (p % 3) * 16384;
    f32x4 a0 = (f32x4){0.f,0.f,0.f,0.f};
    f32x4 a1 = (f32x4){0.f,0.f,0.f,0.f};
    #pragma unroll
    for (int kk = 0; kk < 8; ++kk) {
      bf16x8 wf = *(const bf16x8*)(buf + (wn + l15) * 512 + ((kk*64 + lh*16) ^ xr));
      a0 = __builtin_amdgcn_mfma_f32_16x16x32_bf16(wf, paf[0][kk], a0, 0, 0, 0);
      a1 = __builtin_amdgcn_mfma_f32_16x16x32_bf16(wf, paf[1][kk], a1, 0, 0, 0);
    }
    const int cloc = j * 32 + wn + lh * 4;
    f32x4 o0, o1;
    #pragma unroll
    for (int jj = 0; jj < 4; ++jj) {
      o0[jj] = a0[jj] + pbR[jj] + rR0[jj];
      o1[jj] = a1[jj] + pbR[jj] + rR1[jj];
      ls0 += o0[jj]; lq0 += o0[jj] * o0[jj];
      ls1 += o1[jj]; lq1 += o1[jj] * o1[jj];
    }
    *(f32x4*)(X1 + pixA0 + cloc) = o0;
    *(f32x4*)(X1 + pixA1 + cloc) = o1;
    {   // stash x1 values (bf16) in ldsH for LN2
      union { bf16 hh[4]; uint2 u; } q0, q1;
      #pragma unroll
      for (int jj = 0; jj < 4; ++jj) {
        q0.hh[jj] = __float2bfloat16(o0[jj]);
        q1.hh[jj] = __float2bfloat16(o1[jj]);
      }
      int r0 = wr + l15, r1 = wr + 16 + l15;
      *(uint2*)(ldsH + r0 * 512 + ((cloc * 2) ^ ((r0 & 7) << 4))) = q0.u;
      *(uint2*)(ldsH + r1 * 512 + ((cloc * 2) ^ ((r1 & 7) << 4))) = q1.u;
    }
    if (j < 7) { pbR = pbN; rR0 = rN0; rR1 = rN1; }
    if (p < 39) {
      asm volatile("s_waitcnt vmcnt(4) lgkmcnt(0)" ::: "memory");
      __builtin_amdgcn_sched_barrier(0);
    }
  }

  // LN2 row sums: reduce over lh (cols), publish per row-half
  ls0 += __shfl_xor(ls0, 16); ls0 += __shfl_xor(ls0, 32);
  lq0 += __shfl_xor(lq0, 16); lq0 += __shfl_xor(lq0, 32);
  ls1 += __shfl_xor(ls1, 16); ls1 += __shfl_xor(ls1, 32);
  lq1 += __shfl_xor(lq1, 16); lq1 += __shfl_xor(lq1, 32);
  if (lh == 0) {
    ((float2*)sums)[(wr + l15) * 2 + (wid & 1)]      = make_float2(ls0, lq0);
    ((float2*)sums)[(wr + 16 + l15) * 2 + (wid & 1)] = make_float2(ls1, lq1);
  }
  __syncthreads();

  // LN2 appendix: each wave normalizes 16 rows, writes ln2out (pixel-major)
  {
    f32x4 sR = *(const f32x4*)(ln2s + lane * 4);
    f32x4 bR = *(const f32x4*)(ln2b + lane * 4);
    for (int rr = 0; rr < 16; ++rr) {
      int row = wid * 16 + rr;
      float2 c0 = ((float2*)sums)[row * 2 + 0];
      float2 c1 = ((float2*)sums)[row * 2 + 1];
      float mu = (c0.x + c1.x) * (1.0f / 256.0f);
      float rs = rsqrtf((c0.y + c1.y) * (1.0f / 256.0f) - mu * mu + 1e-5f);
      union { uint2 u; bf16 hh[4]; } xin;
      xin.u = *(const uint2*)(ldsH + row * 512 + ((lane * 8) ^ ((row & 7) << 4)));
      union { bf16 hh[4]; uint2 u; } pk;
      #pragma unroll
      for (int jj = 0; jj < 4; ++jj)
        pk.hh[jj] = __float2bfloat16((__bfloat162float(xin.hh[jj]) - mu) * rs * sR[jj] + bR[jj]);
      *(uint2*)(ln2out + remap(tb + row) + lane * 4) = pk.u;
    }
  }
}

// ============ FUSED MLP (unchanged from R12): 512 thr, 256 rows, depth-3 ring ============
__global__ __launch_bounds__(512, 2) void k_mlp(
    const bf16* __restrict__ A, const bf16* __restrict__ W1,
    const float* __restrict__ B1, const bf16* __restrict__ W2,
    const float* __restrict__ B2, float* __restrict__ X1)
{
  __shared__ __align__(16) char lds[122880];

  const int tid = threadIdx.x;
  const int wid = tid >> 6;
  const int lane = tid & 63;
  const int l15 = lane & 15, lh = lane >> 4;
  const int rowBase = blockIdx.x * 256 + wid * 32;
  char* scr   = lds + 98304 + wid * 2560;
  char* b1lds = lds + 118784;

  auto stage_w1 = [&](int c) {
    char* slot = lds + (c % 3) * 32768;
    const char* srcW1 = (const char*)W1 + (size_t)c * 32 * 512;
    #pragma unroll
    for (int i = 0; i < 2; ++i) {
      int off = (i * 512 + tid) * 16;
      int r = off >> 9, cb = off & 511;
      int csw = cb ^ ((r & 7) << 4);
      gload_lds16(srcW1 + (size_t)r * 512 + csw, slot + off);
    }
  };
  auto stage_w2 = [&](int c) {
    char* dst = lds + ((c + 1) % 3) * 32768 + 16384;
    #pragma unroll
    for (int i = 0; i < 2; ++i) {
      int off = (i * 512 + tid) * 16;
      int ch = off >> 12, row = (off >> 4) & 255;
      gload_lds16((const char*)W2 + (size_t)row * 2048 + (size_t)c * 64 + ch * 16,
                  dst + off);
    }
  };

  if (tid < 256) gload_lds16((const char*)B1 + tid * 16, b1lds + tid * 16);
  bf16x8 af[2][8];
  {
    const bf16* a0 = A + (size_t)(rowBase + l15) * 256 + lh * 8;
    #pragma unroll
    for (int kk = 0; kk < 8; ++kk) {
      af[0][kk] = *(const bf16x8*)(a0 + kk * 32);
      af[1][kk] = *(const bf16x8*)(a0 + 4096 + kk * 32);
    }
  }
  stage_w1(0);
  stage_w1(1);
  stage_w2(0);
  asm volatile("s_waitcnt vmcnt(4)" ::: "memory");
  __builtin_amdgcn_sched_barrier(0);

  f32x4 acc2[2][16];
  #pragma unroll
  for (int m = 0; m < 2; ++m)
    #pragma unroll
    for (int n = 0; n < 16; ++n) acc2[m][n] = (f32x4){0.f,0.f,0.f,0.f};
  bf16x8 actfA = {}, actfB = {};

  for (int c = 0; c < 32; ++c) {
    __builtin_amdgcn_s_barrier();
    __builtin_amdgcn_sched_barrier(0);

    if (c + 2 < 32) stage_w1(c + 2);
    if (c + 1 < 32) stage_w2(c + 1);

    const char* slot  = lds + (c % 3) * 32768;
    const char* w2buf = slot + 16384;
    const int xr = (l15 & 7) << 4;
    const int base0 = l15 * 512;
    const int w2k = lh * 4096;
    f32x4 a00 = (f32x4){0.f,0.f,0.f,0.f};
    f32x4 a10 = (f32x4){0.f,0.f,0.f,0.f};
    f32x4 a01 = (f32x4){0.f,0.f,0.f,0.f};
    f32x4 a11 = (f32x4){0.f,0.f,0.f,0.f};
    if (c > 0) {
      #pragma unroll
      for (int kk = 0; kk < 8; ++kk) {
        const int ko = (kk * 64 + lh * 16) ^ xr;
        bf16x8 b0 = *(const bf16x8*)(slot + base0 + ko);
        bf16x8 b1 = *(const bf16x8*)(slot + base0 + 8192 + ko);
        a00 = __builtin_amdgcn_mfma_f32_16x16x32_bf16(b0, af[0][kk], a00, 0, 0, 0);
        a10 = __builtin_amdgcn_mfma_f32_16x16x32_bf16(b0, af[1][kk], a10, 0, 0, 0);
        a01 = __builtin_amdgcn_mfma_f32_16x16x32_bf16(b1, af[0][kk], a01, 0, 0, 0);
        a11 = __builtin_amdgcn_mfma_f32_16x16x32_bf16(b1, af[1][kk], a11, 0, 0, 0);
        bf16x8 w0 = *(const bf16x8*)(w2buf + w2k + ((2*kk)   * 16 + l15) * 16);
        bf16x8 w1f= *(const bf16x8*)(w2buf + w2k + ((2*kk+1) * 16 + l15) * 16);
        acc2[0][2*kk]   = __builtin_amdgcn_mfma_f32_16x16x32_bf16(w0,  actfA, acc2[0][2*kk],   0, 0, 0);
        acc2[1][2*kk]   = __builtin_amdgcn_mfma_f32_16x16x32_bf16(w0,  actfB, acc2[1][2*kk],   0, 0, 0);
        acc2[0][2*kk+1] = __builtin_amdgcn_mfma_f32_16x16x32_bf16(w1f, actfA, acc2[0][2*kk+1], 0, 0, 0);
        acc2[1][2*kk+1] = __builtin_amdgcn_mfma_f32_16x16x32_bf16(w1f, actfB, acc2[1][2*kk+1], 0, 0, 0);
      }
    } else {
      #pragma unroll
      for (int kk = 0; kk < 8; ++kk) {
        const int ko = (kk * 64 + lh * 16) ^ xr;
        bf16x8 b0 = *(const bf16x8*)(slot + base0 + ko);
        bf16x8 b1 = *(const bf16x8*)(slot + base0 + 8192 + ko);
        a00 = __builtin_amdgcn_mfma_f32_16x16x32_bf16(b0, af[0][kk], a00, 0, 0, 0);
        a10 = __builtin_amdgcn_mfma_f32_16x16x32_bf16(b0, af[1][kk], a10, 0, 0, 0);
        a01 = __builtin_amdgcn_mfma_f32_16x16x32_bf16(b1, af[0][kk], a01, 0, 0, 0);
        a11 = __builtin_amdgcn_mfma_f32_16x16x32_bf16(b1, af[1][kk], a11, 0, 0, 0);
      }
    }

    f32x4 bv0 = *(const f32x4*)(b1lds + c * 128 + lh * 16);
    f32x4 bv1 = *(const f32x4*)(b1lds + c * 128 + 64 + lh * 16);
    auto gelu = [](float v) -> bf16 {
      float w = fmaf(v * v, 0.1029434f, 2.3022083f);
      float e = __builtin_amdgcn_exp2f(-v * w);
      return __float2bfloat16(v * __builtin_amdgcn_rcpf(1.0f + e));
    };
    union { bf16 h[4]; uint2 u; } p00, p01, p10, p11;
    #pragma unroll
    for (int j = 0; j < 4; ++j) {
      p00.h[j] = gelu(a00[j] + bv0[j]);
      p01.h[j] = gelu(a01[j] + bv1[j]);
      p10.h[j] = gelu(a10[j] + bv0[j]);
      p11.h[j] = gelu(a11[j] + bv1[j]);
    }
    *(uint2*)(scr + l15 * 80 + lh * 8)             = p00.u;
    *(uint2*)(scr + l15 * 80 + 32 + lh * 8)        = p01.u;
    *(uint2*)(scr + (16 + l15) * 80 + lh * 8)      = p10.u;
    *(uint2*)(scr + (16 + l15) * 80 + 32 + lh * 8) = p11.u;
    actfA = *(const bf16x8*)(scr + l15 * 80 + lh * 16);
    actfB = *(const bf16x8*)(scr + (16 + l15) * 80 + lh * 16);

    if (c <= 29)      { asm volatile("s_waitcnt vmcnt(4)" ::: "memory"); }
    else if (c == 30) { asm volatile("s_waitcnt vmcnt(2)" ::: "memory"); }
    else              { asm volatile("s_waitcnt vmcnt(0)" ::: "memory"); }
    __builtin_amdgcn_sched_barrier(0);
  }

  __builtin_amdgcn_s_barrier();
  {
    const char* w2buf = lds + 2 * 32768 + 16384;
    const int w2k = lh * 4096;
    #pragma unroll
    for (int n = 0; n < 16; ++n) {
      bf16x8 wf = *(const bf16x8*)(w2buf + w2k + (n * 16 + l15) * 16);
      acc2[0][n] = __builtin_amdgcn_mfma_f32_16x16x32_bf16(wf, actfA, acc2[0][n], 0, 0, 0);
      acc2[1][n] = __builtin_amdgcn_mfma_f32_16x16x32_bf16(wf, actfB, acc2[1][n], 0, 0, 0);
    }
  }

  #pragma unroll
  for (int m = 0; m < 2; ++m) {
    size_t rowAddr = (size_t)(rowBase + m * 16 + l15) * 256;
    #pragma unroll
    for (int n = 0; n < 16; ++n) {
      const int colb = n * 16 + lh * 4;
      const f32x4 b4 = *(const f32x4*)(B2 + colb);
      f32x4* p = (f32x4*)(X1 + rowAddr + colb);
      f32x4 cc = *p;
      #pragma unroll
      for (int j = 0; j < 4; ++j) cc[j] += acc2[m][n][j] + b4[j];
      *p = cc;
    }
  }
}

// ---------------- launch ----------------
extern "C" void kernel_launch(void* const* d_in, const int* in_sizes, int n_in,
                              void* d_out, int out_size, void* d_ws, size_t ws_size,
                              hipStream_t stream) {
  (void)in_sizes; (void)n_in; (void)out_size; (void)ws_size;
  const float* x      = (const float*)d_in[0];
  const float* ln1_s  = (const float*)d_in[1];
  const float* ln1_b  = (const float*)d_in[2];
  const float* qkv_w  = (const float*)d_in[3];
  const float* qkv_b  = (const float*)d_in[4];
  const float* proj_w = (const float*)d_in[5];
  const float* proj_b = (const float*)d_in[6];
  const float* rel_b  = (const float*)d_in[7];
  const float* ln2_s  = (const float*)d_in[8];
  const float* ln2_b  = (const float*)d_in[9];
  const float* w1     = (const float*)d_in[10];
  const float* b1     = (const float*)d_in[11];
  const float* w2     = (const float*)d_in[12];
  const float* b2     = (const float*)d_in[13];

  char* ws = (char*)d_ws;
  bf16*  wqkv  = (bf16*)(ws + 0);               // 196608 el
  bf16*  wproj = wqkv + 196608;                 // 65536 el
  bf16*  wm1   = wqkv + 262144;                 // 262144 el
  bf16*  wm2   = wqkv + 524288;                 // 262144 el
  float* btab  = (float*)(ws + 1572864);        // 32768 f32
  bf16*  hbuf  = (bf16*)(ws + 2097152);         // 65536x256 (pre-swizzled rows)
  bf16*  ln2buf= (bf16*)(ws + 35651584);        // 65536x256 (pixel-major)
  float* x1    = (float*)d_out;                 // residual lives in d_out

  k_conv_weights<<<3072, 256, 0, stream>>>(qkv_w, proj_w, w1, w2, wqkv);
  k_build_btab<<<128, 256, 0, stream>>>(rel_b, btab);
  k_ln1_window<<<16384, 256, 0, stream>>>(x, ln1_s, ln1_b, hbuf);
  k_win<<<1024, 256, 0, stream>>>(hbuf, wqkv, qkv_b, btab, wproj, proj_b,
                                  x, ln2_s, ln2_b, x1, ln2buf);
  k_mlp<<<256, 512, 0, stream>>>(ln2buf, wm1, b1, wm2, b2, x1);
}